// Round 14
// baseline (262.547 us; speedup 1.0000x reference)
//
#include <hip/hip_runtime.h>
#include <hip/hip_bf16.h>

#define N_NODES 10000
#define N_EDGES 160000
#define FEAT 512
#define D 128
#define NRBF 20
#define RCUT 1.4415f
#define CAP 64          // max degree bucket (Poisson(16): P(deg>64) ~ 1e-20)

typedef __attribute__((ext_vector_type(8))) short bf16x8;
typedef __attribute__((ext_vector_type(4))) float f32x4;

__device__ __forceinline__ float silu_f(float x) { return x / (1.0f + __expf(-x)); }
__device__ __forceinline__ float s2f(short s) {
    unsigned int u = ((unsigned int)(unsigned short)s) << 16;
    float f; __builtin_memcpy(&f, &u, 4); return f;
}
__device__ __forceinline__ short f2s(float f) {
    __hip_bfloat16 h = __float2bfloat16(f);
    short s; __builtin_memcpy(&s, &h, 2); return s;
}
__device__ __forceinline__ float asf(unsigned int u) {
    float f; __builtin_memcpy(&f, &u, 4); return f;
}

// ================================================================ k_prep
// b 0..87: pack weights to MFMA B-frag order; b 88: W2 transpose; b 89+: CSR+basis
__global__ __launch_bounds__(256) void k_prep(
    const float* __restrict__ W1, const float* __restrict__ W3,
    const float* __restrict__ U,  const float* __restrict__ V,
    const float* __restrict__ Wu1, const float* __restrict__ Wu2,
    const float* __restrict__ W2,
    short* __restrict__ W1p, short* __restrict__ W3p,
    short* __restrict__ Up,  short* __restrict__ Vp,
    short* __restrict__ Wu1p, short* __restrict__ Wu2p,
    float* __restrict__ W2t,
    const int* __restrict__ ei, const float* __restrict__ ea2,
    int* __restrict__ cnt, unsigned int* __restrict__ slot,
    __hip_bfloat16* __restrict__ basis)
{
    int b = blockIdx.x;
    if (b < 88) {
        const float* W; short* Wp; int K, N;
        if      (b < 8)  { W = W1;  Wp = W1p;  K = 128; N = 128; }
        else if (b < 32) { W = W3;  Wp = W3p;  K = 128; N = 384; b -= 8;  }
        else if (b < 40) { W = U;   Wp = Up;   K = 128; N = 128; b -= 32; }
        else if (b < 48) { W = V;   Wp = Vp;   K = 128; N = 128; b -= 40; }
        else if (b < 64) { W = Wu1; Wp = Wu1p; K = 256; N = 128; b -= 48; }
        else             { W = Wu2; Wp = Wu2p; K = 128; N = 384; b -= 64; }
        int idx = b * 256 + threadIdx.x;
        int NT = N >> 4;
        int total = (K >> 5) * NT * 64;
        if (idx >= total) return;
        int lane = idx & 63, fid = idx >> 6;
        int ks = fid / NT, ct = fid % NT;
        int k0 = ks * 32 + ((lane >> 4) << 3);
        int c  = ct * 16 + (lane & 15);
        short* o = Wp + (size_t)idx * 8;
        #pragma unroll
        for (int j = 0; j < 8; ++j)
            o[j] = f2s(W[(size_t)(k0 + j) * N + c]);
        return;
    }
    if (b == 88) {   // W2t[c*20+n] = W2[n*384+c]  (384x20 fp32, column-contiguous)
        for (int i = threadIdx.x; i < 384 * NRBF; i += 256) {
            int c = i / NRBF, n = i % NRBF;
            W2t[i] = W2[n * 384 + c];
        }
        return;
    }
    int e = (b - 89) * 256 + threadIdx.x;
    if (e >= N_EDGES) return;
    int d = ei[N_EDGES + e];
    int pos = atomicAdd(&cnt[d], 1);
    if (pos < CAP)
        slot[d * CAP + pos] = (((unsigned int)e) << 14) | (unsigned int)ei[e];

    float r  = ea2[e];
    float pr = 3.14159265358979f * r / RCUT;
    float cosv = __cosf(pr);
    float cut  = 0.5f * (cosv + 1.0f) * (r < RCUT ? 1.0f : 0.0f);
    float pref = sqrtf(2.0f / RCUT) / r * cut;
    float c2 = 2.0f * cosv;
    float sm1 = 0.0f, s = __sinf(pr);
    #pragma unroll
    for (int n = 0; n < NRBF; ++n) {
        basis[(size_t)e * NRBF + n] = __float2bfloat16(pref * s);
        float nx = c2 * s - sm1; sm1 = s; s = nx;
    }
}

// ================================================================ k_A (MFMA)
// P1 row = 768 bf16 (1536 B). Thread t's 6 shorts at [t*6]:
//   [0]=A[t], [1]=A[128+t], [2]=A[256+t], [3]=xv c0, [4]=xv c1, [5]=xv c2
#define LDSP 136
__global__ __launch_bounds__(256) void k_A_mfma(
    const float* __restrict__ x,
    const short* __restrict__ W1p, const float* __restrict__ b1,
    const short* __restrict__ W3p, const float* __restrict__ b3,
    __hip_bfloat16* __restrict__ P1)
{
    __shared__ __align__(16) short sj[16 * LDSP];
    __shared__ __align__(16) short tt[16 * LDSP];
    const int t = threadIdx.x;
    const int lane = t & 63, wave = t >> 6;
    const int n0 = blockIdx.x * 16;

    for (int i = t; i < 16 * 128; i += 256) {
        int e = i >> 7, j = i & 127;
        sj[e * LDSP + j] = f2s(x[(size_t)(n0 + e) * FEAT + 384 + j]);
    }
    // xv pack -> P1 slots 3..5
    for (int i = t; i < 16 * 384; i += 256) {
        int e = i / 384, o = i % 384;
        int j = o & 127, c = o >> 7;
        P1[(size_t)(n0 + e) * 768 + j * 6 + 3 + c] =
            __float2bfloat16(x[(size_t)(n0 + e) * FEAT + 3 * j + c]);
    }
    __syncthreads();

    // GEMM1: T = silu(sj @ W1 + b1)
    {
        f32x4 acc[2];
        #pragma unroll
        for (int q = 0; q < 2; ++q) acc[q] = (f32x4){0.f, 0.f, 0.f, 0.f};
        for (int ks = 0; ks < 4; ++ks) {
            bf16x8 a = *(const bf16x8*)&sj[(lane & 15) * LDSP + ks * 32 + ((lane >> 4) << 3)];
            #pragma unroll
            for (int q = 0; q < 2; ++q) {
                bf16x8 b = ((const bf16x8*)W1p)[((size_t)ks * 8 + wave * 2 + q) * 64 + lane];
                acc[q] = __builtin_amdgcn_mfma_f32_16x16x32_bf16(a, b, acc[q], 0, 0, 0);
            }
        }
        #pragma unroll
        for (int q = 0; q < 2; ++q) {
            int col = (wave * 2 + q) * 16 + (lane & 15);
            int row = (lane >> 4) << 2;
            float bb = b1[col];
            #pragma unroll
            for (int r = 0; r < 4; ++r)
                tt[(row + r) * LDSP + col] = f2s(silu_f(acc[q][r] + bb));
        }
    }
    __syncthreads();

    // GEMM2: A = T @ W3 + b3 -> P1 slots 0..2
    {
        f32x4 acc[6];
        #pragma unroll
        for (int q = 0; q < 6; ++q) acc[q] = (f32x4){0.f, 0.f, 0.f, 0.f};
        for (int ks = 0; ks < 4; ++ks) {
            bf16x8 a = *(const bf16x8*)&tt[(lane & 15) * LDSP + ks * 32 + ((lane >> 4) << 3)];
            #pragma unroll
            for (int q = 0; q < 6; ++q) {
                bf16x8 b = ((const bf16x8*)W3p)[((size_t)ks * 24 + wave * 6 + q) * 64 + lane];
                acc[q] = __builtin_amdgcn_mfma_f32_16x16x32_bf16(a, b, acc[q], 0, 0, 0);
            }
        }
        #pragma unroll
        for (int q = 0; q < 6; ++q) {
            int col = (wave * 6 + q) * 16 + (lane & 15);
            int row = (lane >> 4) << 2;
            float bb = b3[col];
            #pragma unroll
            for (int r = 0; r < 4; ++r)
                P1[(size_t)(n0 + row + r) * 768 + (col & 127) * 6 + (col >> 7)] =
                    __float2bfloat16(acc[q][r] + bb);
        }
    }
}

// ================================================================ k_B (MFMA)
__global__ __launch_bounds__(256) void k_B_mfma(
    const short* __restrict__ Up, const short* __restrict__ Vp,
    const short* __restrict__ Wu1p, const float* __restrict__ bu1,
    const short* __restrict__ Wu2p, const float* __restrict__ bu2,
    const float* __restrict__ xin,
    __hip_bfloat16* __restrict__ M2)
{
    __shared__ __align__(16) short XV[48 * LDSP];
    __shared__ __align__(16) short VU[48 * LDSP];
    __shared__ __align__(16) short S [16 * LDSP];
    __shared__ __align__(16) short NRM[16 * LDSP];
    __shared__ __align__(16) short H1[16 * LDSP];
    __shared__ __align__(16) short A1[16 * LDSP];
    __shared__ __align__(16) short A3[16 * LDSP];

    const int t = threadIdx.x, lane = t & 63, wave = t >> 6;
    const int n0 = blockIdx.x * 16;

    for (int i = t; i < 16 * 512; i += 256) {
        int e = i >> 9, f = i & 511;
        short sv = f2s(xin[(size_t)(n0 + e) * FEAT + f]);
        if (f < 384) XV[(e * 3 + (f >> 7)) * LDSP + (f & 127)] = sv;
        else         S[e * LDSP + (f - 384)] = sv;
    }
    __syncthreads();

    // GEMM-U: VU = XV @ U
    {
        f32x4 acc[3][2];
        #pragma unroll
        for (int rt = 0; rt < 3; ++rt)
            #pragma unroll
            for (int q = 0; q < 2; ++q) acc[rt][q] = (f32x4){0.f, 0.f, 0.f, 0.f};
        for (int ks = 0; ks < 4; ++ks) {
            bf16x8 b[2];
            #pragma unroll
            for (int q = 0; q < 2; ++q)
                b[q] = ((const bf16x8*)Up)[((size_t)ks * 8 + wave * 2 + q) * 64 + lane];
            #pragma unroll
            for (int rt = 0; rt < 3; ++rt) {
                bf16x8 a = *(const bf16x8*)&XV[(rt * 16 + (lane & 15)) * LDSP + ks * 32 + ((lane >> 4) << 3)];
                #pragma unroll
                for (int q = 0; q < 2; ++q)
                    acc[rt][q] = __builtin_amdgcn_mfma_f32_16x16x32_bf16(a, b[q], acc[rt][q], 0, 0, 0);
            }
        }
        #pragma unroll
        for (int rt = 0; rt < 3; ++rt)
            #pragma unroll
            for (int q = 0; q < 2; ++q) {
                int col = (wave * 2 + q) * 16 + (lane & 15);
                int row = rt * 16 + ((lane >> 4) << 2);
                #pragma unroll
                for (int r = 0; r < 4; ++r)
                    VU[(row + r) * LDSP + col] = f2s(acc[rt][q][r]);
            }
    }
    __syncthreads();

    // GEMM-V: VV = VU @ V -> XV
    {
        f32x4 acc[3][2];
        #pragma unroll
        for (int rt = 0; rt < 3; ++rt)
            #pragma unroll
            for (int q = 0; q < 2; ++q) acc[rt][q] = (f32x4){0.f, 0.f, 0.f, 0.f};
        for (int ks = 0; ks < 4; ++ks) {
            bf16x8 b[2];
            #pragma unroll
            for (int q = 0; q < 2; ++q)
                b[q] = ((const bf16x8*)Vp)[((size_t)ks * 8 + wave * 2 + q) * 64 + lane];
            #pragma unroll
            for (int rt = 0; rt < 3; ++rt) {
                bf16x8 a = *(const bf16x8*)&VU[(rt * 16 + (lane & 15)) * LDSP + ks * 32 + ((lane >> 4) << 3)];
                #pragma unroll
                for (int q = 0; q < 2; ++q)
                    acc[rt][q] = __builtin_amdgcn_mfma_f32_16x16x32_bf16(a, b[q], acc[rt][q], 0, 0, 0);
            }
        }
        __syncthreads();
        #pragma unroll
        for (int rt = 0; rt < 3; ++rt)
            #pragma unroll
            for (int q = 0; q < 2; ++q) {
                int col = (wave * 2 + q) * 16 + (lane & 15);
                int row = rt * 16 + ((lane >> 4) << 2);
                #pragma unroll
                for (int r = 0; r < 4; ++r)
                    XV[(row + r) * LDSP + col] = f2s(acc[rt][q][r]);
            }
    }
    __syncthreads();

    for (int i = t; i < 16 * 128; i += 256) {
        int nl = i >> 7, j = i & 127;
        float s = 0.f;
        #pragma unroll
        for (int c = 0; c < 3; ++c) {
            int q = 3 * j + c;
            float f = s2f(XV[(nl * 3 + (q >> 7)) * LDSP + (q & 127)]);
            s += f * f;
        }
        NRM[nl * LDSP + j] = f2s(sqrtf(s));
    }
    __syncthreads();

    // GEMM-Wu1: H1 = silu([NRM | S] @ Wu1 + bu1)
    {
        f32x4 acc[2];
        #pragma unroll
        for (int q = 0; q < 2; ++q) acc[q] = (f32x4){0.f, 0.f, 0.f, 0.f};
        for (int ks = 0; ks < 8; ++ks) {
            const short* asrc = (ks < 4) ? NRM : S;
            int k0 = (ks & 3) * 32;
            bf16x8 a = *(const bf16x8*)&asrc[(lane & 15) * LDSP + k0 + ((lane >> 4) << 3)];
            #pragma unroll
            for (int q = 0; q < 2; ++q) {
                bf16x8 b = ((const bf16x8*)Wu1p)[((size_t)ks * 8 + wave * 2 + q) * 64 + lane];
                acc[q] = __builtin_amdgcn_mfma_f32_16x16x32_bf16(a, b, acc[q], 0, 0, 0);
            }
        }
        #pragma unroll
        for (int q = 0; q < 2; ++q) {
            int col = (wave * 2 + q) * 16 + (lane & 15);
            int row = (lane >> 4) << 2;
            float bb = bu1[col];
            #pragma unroll
            for (int r = 0; r < 4; ++r)
                H1[(row + r) * LDSP + col] = f2s(silu_f(acc[q][r] + bb));
        }
    }
    __syncthreads();

    // GEMM-Wu2: A1 / A3 tiles
    {
        f32x4 acc[4];
        #pragma unroll
        for (int q = 0; q < 4; ++q) acc[q] = (f32x4){0.f, 0.f, 0.f, 0.f};
        for (int ks = 0; ks < 4; ++ks) {
            bf16x8 a = *(const bf16x8*)&H1[(lane & 15) * LDSP + ks * 32 + ((lane >> 4) << 3)];
            #pragma unroll
            for (int q = 0; q < 4; ++q) {
                int w = wave * 4 + q;
                int ctp = (w < 8) ? w : (16 + (w - 8));
                bf16x8 b = ((const bf16x8*)Wu2p)[((size_t)ks * 24 + ctp) * 64 + lane];
                acc[q] = __builtin_amdgcn_mfma_f32_16x16x32_bf16(a, b, acc[q], 0, 0, 0);
            }
        }
        #pragma unroll
        for (int q = 0; q < 4; ++q) {
            int w = wave * 4 + q;
            int colloc = (w & 7) * 16 + (lane & 15);
            int row = (lane >> 4) << 2;
            short* dst = (w < 8) ? A1 : A3;
            float bb = bu2[((w < 8) ? 0 : 256) + colloc];
            #pragma unroll
            for (int r = 0; r < 4; ++r)
                dst[(row + r) * LDSP + colloc] = f2s(acc[q][r] + bb);
        }
    }
    __syncthreads();

    for (int i = t; i < 16 * 128; i += 256) {
        int nl = i >> 7, j = i & 127;
        float a1v = s2f(A1[nl * LDSP + j]);
        float a3v = s2f(A3[nl * LDSP + j]);
        __hip_bfloat16* mrow = M2 + (size_t)(n0 + nl) * FEAT;
        float dot = 0.f;
        #pragma unroll
        for (int c = 0; c < 3; ++c) {
            int q = 3 * j + c;
            int rr = nl * 3 + (q >> 7), cc = q & 127;
            float vu_ = s2f(VU[rr * LDSP + cc]);
            float vv_ = s2f(XV[rr * LDSP + cc]);
            float vf = vu_ * a1v;
            dot += vf * vv_;
            mrow[c * 128 + j] = __float2bfloat16(vf);
        }
        mrow[384 + j] = __float2bfloat16(dot + a3v);
    }
}

// ================================================================ k_gather1
// Round-12 structure; W2 accessed via transposed W2t with float4 loads
// (15 loads vs 60 scalar re-loads per edge). ebl reads unchanged (scalar).
__global__ __launch_bounds__(128, 4) void k_gather1(
    const float* __restrict__ x,
    const __hip_bfloat16* __restrict__ P1,
    const __hip_bfloat16* __restrict__ basis,
    const float* __restrict__ ea1,
    const float* __restrict__ W2t, const float* __restrict__ b2,
    const int* __restrict__ cnt, const unsigned int* __restrict__ slot,
    float* __restrict__ out)
{
    __shared__ float ebl[CAP][NRBF];
    __shared__ float eall[CAP][3];
    __shared__ int srcl[CAP], ell[CAP];

    const int d = blockIdx.x, t = threadIdx.x;   // 128 threads

    const float* w2ra = W2t + (size_t)t * NRBF;          // 20 contiguous floats
    const float* w2rb = W2t + (size_t)(128 + t) * NRBF;
    const float* w2rc = W2t + (size_t)(256 + t) * NRBF;
    const float b2a = b2[t], b2b = b2[128 + t], b2c = b2[256 + t];

    const int deg = min(cnt[d], CAP);
    if (t < deg) {
        unsigned int p = slot[d * CAP + t];
        srcl[t] = (int)(p & 16383u);
        ell[t]  = (int)(p >> 14);
    }
    __syncthreads();
    for (int i = t; i < deg * NRBF; i += 128)
        ebl[i / NRBF][i % NRBF] = __bfloat162float(basis[(size_t)ell[i / NRBF] * NRBF + (i % NRBF)]);
    for (int i = t; i < deg * 3; i += 128)
        eall[i / 3][i % 3] = ea1[(size_t)ell[i / 3] * 3 + (i % 3)];
    __syncthreads();

    float acc0 = 0.f, acc1 = 0.f, acc2 = 0.f, accs = 0.f;

    for (int base = 0; base < deg; base += 8) {
        // prefetch 8 edges x 12 B (one row stream, no pad)
        unsigned int f0[8], f1[8], f2[8];
        #pragma unroll
        for (int ee = 0; ee < 8; ++ee) {
            int idx = (base + ee < deg) ? (base + ee) : base;
            const unsigned int* rp =
                (const unsigned int*)((const char*)P1 + (size_t)srcl[idx] * 1536) + t * 3;
            f0[ee] = rp[0]; f1[ee] = rp[1]; f2[ee] = rp[2];
        }
        #pragma unroll
        for (int ee = 0; ee < 8; ++ee) {
            if (base + ee >= deg) break;     // uniform per block
            const int ix = base + ee;
            float ebA = b2a, ebB = b2b, ebC = b2c;
            #pragma unroll
            for (int n4 = 0; n4 < 5; ++n4) {
                float4 wa = *(const float4*)(w2ra + n4 * 4);
                float4 wb = *(const float4*)(w2rb + n4 * 4);
                float4 wc = *(const float4*)(w2rc + n4 * 4);
                float e0 = ebl[ix][n4 * 4], e1 = ebl[ix][n4 * 4 + 1];
                float e2 = ebl[ix][n4 * 4 + 2], e3 = ebl[ix][n4 * 4 + 3];
                ebA += e0 * wa.x + e1 * wa.y + e2 * wa.z + e3 * wa.w;
                ebB += e0 * wb.x + e1 * wb.y + e2 * wb.z + e3 * wb.w;
                ebC += e0 * wc.x + e1 * wc.y + e2 * wc.z + e3 * wc.w;
            }
            float a1 = asf(f0[ee] << 16), a2 = asf(f0[ee] & 0xffff0000u);
            float a3 = asf(f1[ee] << 16), x0 = asf(f1[ee] & 0xffff0000u);
            float x1 = asf(f2[ee] << 16), x2 = asf(f2[ee] & 0xffff0000u);
            float s1 = a1 * ebA;
            float s2 = a2 * ebB;
            float s3 = a3 * ebC;
            acc0 += x0 * s1 + s3 * eall[ix][0];
            acc1 += x1 * s1 + s3 * eall[ix][1];
            acc2 += x2 * s1 + s3 * eall[ix][2];
            accs += s2;
        }
    }

    const size_t ro = (size_t)d * FEAT;
    out[ro + 3 * t]     = x[ro + 3 * t]     + acc0;
    out[ro + 3 * t + 1] = x[ro + 3 * t + 1] + acc1;
    out[ro + 3 * t + 2] = x[ro + 3 * t + 2] + acc2;
    out[ro + 384 + t]   = x[ro + 384 + t]   + accs;
}

// ================================================================ k_gather2
// 2 half-block groups over edges; uint2 loads, 8-deep prefetch; LDS combine.
__global__ __launch_bounds__(256) void k_gather2(
    const __hip_bfloat16* __restrict__ M2,
    const int* __restrict__ cnt, const unsigned int* __restrict__ slot,
    float* __restrict__ out)
{
    __shared__ float part[2][FEAT];
    __shared__ int sl[CAP];
    const int d = blockIdx.x, t = threadIdx.x;
    const int tt = t & 127, g = t >> 7;
    const int deg = min(cnt[d], CAP);
    if (t < deg) sl[t] = (int)(slot[d * CAP + t] & 16383u);
    __syncthreads();

    float a0 = 0.f, a1 = 0.f, a2 = 0.f, a3 = 0.f;
    int i = g;
    for (; i + 14 < deg; i += 16) {
        uint2 v[8];
        #pragma unroll
        for (int q = 0; q < 8; ++q)
            v[q] = *(const uint2*)((const char*)M2 + (size_t)sl[i + 2 * q] * 1024 + tt * 8);
        #pragma unroll
        for (int q = 0; q < 8; ++q) {
            a0 += asf(v[q].x << 16); a1 += asf(v[q].x & 0xffff0000u);
            a2 += asf(v[q].y << 16); a3 += asf(v[q].y & 0xffff0000u);
        }
    }
    for (; i < deg; i += 2) {
        uint2 v = *(const uint2*)((const char*)M2 + (size_t)sl[i] * 1024 + tt * 8);
        a0 += asf(v.x << 16); a1 += asf(v.x & 0xffff0000u);
        a2 += asf(v.y << 16); a3 += asf(v.y & 0xffff0000u);
    }
    part[g][tt * 4]     = a0;
    part[g][tt * 4 + 1] = a1;
    part[g][tt * 4 + 2] = a2;
    part[g][tt * 4 + 3] = a3;
    __syncthreads();

    #pragma unroll
    for (int gi = 0; gi < 2; ++gi) {
        int gc = t + gi * 256;
        int m = (gc < 384) ? ((gc % 3) * 128 + gc / 3) : gc;
        out[(size_t)d * FEAT + gc] += part[0][m] + part[1][m];
    }
}

// =================================================================== launch
extern "C" void kernel_launch(void* const* d_in, const int* in_sizes, int n_in,
                              void* d_out, int out_size, void* d_ws, size_t ws_size,
                              hipStream_t stream) {
    (void)in_sizes; (void)n_in; (void)out_size; (void)ws_size;
    const float* x   = (const float*)d_in[0];
    const int*   ei  = (const int*)d_in[1];
    const float* ea1 = (const float*)d_in[2];
    const float* ea2 = (const float*)d_in[3];
    const float* W1  = (const float*)d_in[4];
    const float* b1  = (const float*)d_in[5];
    const float* W2  = (const float*)d_in[6];
    const float* b2  = (const float*)d_in[7];
    const float* W3  = (const float*)d_in[8];
    const float* b3  = (const float*)d_in[9];
    const float* U   = (const float*)d_in[10];
    const float* V   = (const float*)d_in[11];
    const float* Wu1 = (const float*)d_in[12];
    const float* bu1 = (const float*)d_in[13];
    const float* Wu2 = (const float*)d_in[14];
    const float* bu2 = (const float*)d_in[15];
    float* out = (float*)d_out;

    // ws layout (ws proven >= 165 MB in round 3; used ~35 MB)
    char* w = (char*)d_ws;
    __hip_bfloat16* P1    = (__hip_bfloat16*)w;                 // N*768*2 = 15,360,000
    __hip_bfloat16* M2    = (__hip_bfloat16*)(w + 15360000);    // N*512*2 = 10,240,000
    __hip_bfloat16* basis = (__hip_bfloat16*)(w + 25600000);    // E*20*2  =  6,400,000
    short* W1p  = (short*)(w + 32000000);
    short* W3p  = (short*)(w + 32032768);
    short* Upk  = (short*)(w + 32131072);
    short* Vpk  = (short*)(w + 32163840);
    short* Wu1p = (short*)(w + 32196608);
    short* Wu2p = (short*)(w + 32262144);
    int*          cnt  = (int*)(w + 32360448);                  // 40,000
    unsigned int* slot = (unsigned int*)(w + 32400448);         // N*CAP*4 = 2,560,000
    float*        W2t  = (float*)(w + 34960448);                // 384*20*4 = 30,720

    hipMemsetAsync(cnt, 0, N_NODES * sizeof(int), stream);
    k_prep    <<<89 + (N_EDGES + 255) / 256, 256, 0, stream>>>(
        W1, W3, U, V, Wu1, Wu2, W2, W1p, W3p, Upk, Vpk, Wu1p, Wu2p, W2t,
        ei, ea2, cnt, slot, basis);

    k_A_mfma  <<<N_NODES / 16, 256, 0, stream>>>(x, W1p, b1, W3p, b3, P1);
    k_gather1 <<<N_NODES,      128, 0, stream>>>(x, P1, basis, ea1, W2t, b2, cnt, slot, out);
    k_B_mfma  <<<N_NODES / 16, 256, 0, stream>>>(Upk, Vpk, Wu1p, bu1, Wu2p, bu2, out, M2);
    k_gather2 <<<N_NODES,      256, 0, stream>>>(M2, cnt, slot, out);
}

// Round 15
// 233.811 us; speedup vs baseline: 1.1229x; 1.1229x over previous
//
#include <hip/hip_runtime.h>
#include <hip/hip_bf16.h>

#define N_NODES 10000
#define N_EDGES 160000
#define FEAT 512
#define D 128
#define NRBF 20
#define RCUT 1.4415f
#define CAP 64          // max degree bucket (Poisson(16): P(deg>64) ~ 1e-20)

typedef __attribute__((ext_vector_type(8))) short bf16x8;
typedef __attribute__((ext_vector_type(4))) float f32x4;

__device__ __forceinline__ float silu_f(float x) { return x / (1.0f + __expf(-x)); }
__device__ __forceinline__ float s2f(short s) {
    unsigned int u = ((unsigned int)(unsigned short)s) << 16;
    float f; __builtin_memcpy(&f, &u, 4); return f;
}
__device__ __forceinline__ short f2s(float f) {
    __hip_bfloat16 h = __float2bfloat16(f);
    short s; __builtin_memcpy(&s, &h, 2); return s;
}
__device__ __forceinline__ float asf(unsigned int u) {
    float f; __builtin_memcpy(&f, &u, 4); return f;
}

// ================================================================ k_prep
// blocks 0..87: pack weights to MFMA B-frag order; blocks 88..712: CSR fill + basis
__global__ __launch_bounds__(256) void k_prep(
    const float* __restrict__ W1, const float* __restrict__ W3,
    const float* __restrict__ U,  const float* __restrict__ V,
    const float* __restrict__ Wu1, const float* __restrict__ Wu2,
    short* __restrict__ W1p, short* __restrict__ W3p,
    short* __restrict__ Up,  short* __restrict__ Vp,
    short* __restrict__ Wu1p, short* __restrict__ Wu2p,
    const int* __restrict__ ei, const float* __restrict__ ea2,
    int* __restrict__ cnt, unsigned int* __restrict__ slot,
    __hip_bfloat16* __restrict__ basis)
{
    int b = blockIdx.x;
    if (b < 88) {
        const float* W; short* Wp; int K, N;
        if      (b < 8)  { W = W1;  Wp = W1p;  K = 128; N = 128; }
        else if (b < 32) { W = W3;  Wp = W3p;  K = 128; N = 384; b -= 8;  }
        else if (b < 40) { W = U;   Wp = Up;   K = 128; N = 128; b -= 32; }
        else if (b < 48) { W = V;   Wp = Vp;   K = 128; N = 128; b -= 40; }
        else if (b < 64) { W = Wu1; Wp = Wu1p; K = 256; N = 128; b -= 48; }
        else             { W = Wu2; Wp = Wu2p; K = 128; N = 384; b -= 64; }
        int idx = b * 256 + threadIdx.x;
        int NT = N >> 4;
        int total = (K >> 5) * NT * 64;
        if (idx >= total) return;
        int lane = idx & 63, fid = idx >> 6;
        int ks = fid / NT, ct = fid % NT;
        int k0 = ks * 32 + ((lane >> 4) << 3);
        int c  = ct * 16 + (lane & 15);
        short* o = Wp + (size_t)idx * 8;
        #pragma unroll
        for (int j = 0; j < 8; ++j)
            o[j] = f2s(W[(size_t)(k0 + j) * N + c]);
        return;
    }
    int e = (b - 88) * 256 + threadIdx.x;
    if (e >= N_EDGES) return;
    int d = ei[N_EDGES + e];
    int pos = atomicAdd(&cnt[d], 1);
    if (pos < CAP)
        slot[d * CAP + pos] = (((unsigned int)e) << 14) | (unsigned int)ei[e];

    float r  = ea2[e];
    float pr = 3.14159265358979f * r / RCUT;
    float cosv = __cosf(pr);
    float cut  = 0.5f * (cosv + 1.0f) * (r < RCUT ? 1.0f : 0.0f);
    float pref = sqrtf(2.0f / RCUT) / r * cut;
    float c2 = 2.0f * cosv;
    float sm1 = 0.0f, s = __sinf(pr);
    #pragma unroll
    for (int n = 0; n < NRBF; ++n) {
        basis[(size_t)e * NRBF + n] = __float2bfloat16(pref * s);
        float nx = c2 * s - sm1; sm1 = s; s = nx;
    }
}

// ================================================================ k_A (MFMA)
// P1 row = 768 bf16 (1536 B). Thread t's 6 shorts at [t*6]:
//   [0]=A[t], [1]=A[128+t], [2]=A[256+t], [3]=xv c0, [4]=xv c1, [5]=xv c2
#define LDSP 136
__global__ __launch_bounds__(256) void k_A_mfma(
    const float* __restrict__ x,
    const short* __restrict__ W1p, const float* __restrict__ b1,
    const short* __restrict__ W3p, const float* __restrict__ b3,
    __hip_bfloat16* __restrict__ P1)
{
    __shared__ __align__(16) short sj[16 * LDSP];
    __shared__ __align__(16) short tt[16 * LDSP];
    const int t = threadIdx.x;
    const int lane = t & 63, wave = t >> 6;
    const int n0 = blockIdx.x * 16;

    for (int i = t; i < 16 * 128; i += 256) {
        int e = i >> 7, j = i & 127;
        sj[e * LDSP + j] = f2s(x[(size_t)(n0 + e) * FEAT + 384 + j]);
    }
    // xv pack -> P1 slots 3..5
    for (int i = t; i < 16 * 384; i += 256) {
        int e = i / 384, o = i % 384;
        int j = o & 127, c = o >> 7;
        P1[(size_t)(n0 + e) * 768 + j * 6 + 3 + c] =
            __float2bfloat16(x[(size_t)(n0 + e) * FEAT + 3 * j + c]);
    }
    __syncthreads();

    // GEMM1: T = silu(sj @ W1 + b1)
    {
        f32x4 acc[2];
        #pragma unroll
        for (int q = 0; q < 2; ++q) acc[q] = (f32x4){0.f, 0.f, 0.f, 0.f};
        for (int ks = 0; ks < 4; ++ks) {
            bf16x8 a = *(const bf16x8*)&sj[(lane & 15) * LDSP + ks * 32 + ((lane >> 4) << 3)];
            #pragma unroll
            for (int q = 0; q < 2; ++q) {
                bf16x8 b = ((const bf16x8*)W1p)[((size_t)ks * 8 + wave * 2 + q) * 64 + lane];
                acc[q] = __builtin_amdgcn_mfma_f32_16x16x32_bf16(a, b, acc[q], 0, 0, 0);
            }
        }
        #pragma unroll
        for (int q = 0; q < 2; ++q) {
            int col = (wave * 2 + q) * 16 + (lane & 15);
            int row = (lane >> 4) << 2;
            float bb = b1[col];
            #pragma unroll
            for (int r = 0; r < 4; ++r)
                tt[(row + r) * LDSP + col] = f2s(silu_f(acc[q][r] + bb));
        }
    }
    __syncthreads();

    // GEMM2: A = T @ W3 + b3 -> P1 slots 0..2
    {
        f32x4 acc[6];
        #pragma unroll
        for (int q = 0; q < 6; ++q) acc[q] = (f32x4){0.f, 0.f, 0.f, 0.f};
        for (int ks = 0; ks < 4; ++ks) {
            bf16x8 a = *(const bf16x8*)&tt[(lane & 15) * LDSP + ks * 32 + ((lane >> 4) << 3)];
            #pragma unroll
            for (int q = 0; q < 6; ++q) {
                bf16x8 b = ((const bf16x8*)W3p)[((size_t)ks * 24 + wave * 6 + q) * 64 + lane];
                acc[q] = __builtin_amdgcn_mfma_f32_16x16x32_bf16(a, b, acc[q], 0, 0, 0);
            }
        }
        #pragma unroll
        for (int q = 0; q < 6; ++q) {
            int col = (wave * 6 + q) * 16 + (lane & 15);
            int row = (lane >> 4) << 2;
            float bb = b3[col];
            #pragma unroll
            for (int r = 0; r < 4; ++r)
                P1[(size_t)(n0 + row + r) * 768 + (col & 127) * 6 + (col >> 7)] =
                    __float2bfloat16(acc[q][r] + bb);
        }
    }
}

// ================================================================ k_B (MFMA)
__global__ __launch_bounds__(256) void k_B_mfma(
    const short* __restrict__ Up, const short* __restrict__ Vp,
    const short* __restrict__ Wu1p, const float* __restrict__ bu1,
    const short* __restrict__ Wu2p, const float* __restrict__ bu2,
    const float* __restrict__ xin,
    __hip_bfloat16* __restrict__ M2)
{
    __shared__ __align__(16) short XV[48 * LDSP];
    __shared__ __align__(16) short VU[48 * LDSP];
    __shared__ __align__(16) short S [16 * LDSP];
    __shared__ __align__(16) short NRM[16 * LDSP];
    __shared__ __align__(16) short H1[16 * LDSP];
    __shared__ __align__(16) short A1[16 * LDSP];
    __shared__ __align__(16) short A3[16 * LDSP];

    const int t = threadIdx.x, lane = t & 63, wave = t >> 6;
    const int n0 = blockIdx.x * 16;

    for (int i = t; i < 16 * 512; i += 256) {
        int e = i >> 9, f = i & 511;
        short sv = f2s(xin[(size_t)(n0 + e) * FEAT + f]);
        if (f < 384) XV[(e * 3 + (f >> 7)) * LDSP + (f & 127)] = sv;
        else         S[e * LDSP + (f - 384)] = sv;
    }
    __syncthreads();

    // GEMM-U: VU = XV @ U
    {
        f32x4 acc[3][2];
        #pragma unroll
        for (int rt = 0; rt < 3; ++rt)
            #pragma unroll
            for (int q = 0; q < 2; ++q) acc[rt][q] = (f32x4){0.f, 0.f, 0.f, 0.f};
        for (int ks = 0; ks < 4; ++ks) {
            bf16x8 b[2];
            #pragma unroll
            for (int q = 0; q < 2; ++q)
                b[q] = ((const bf16x8*)Up)[((size_t)ks * 8 + wave * 2 + q) * 64 + lane];
            #pragma unroll
            for (int rt = 0; rt < 3; ++rt) {
                bf16x8 a = *(const bf16x8*)&XV[(rt * 16 + (lane & 15)) * LDSP + ks * 32 + ((lane >> 4) << 3)];
                #pragma unroll
                for (int q = 0; q < 2; ++q)
                    acc[rt][q] = __builtin_amdgcn_mfma_f32_16x16x32_bf16(a, b[q], acc[rt][q], 0, 0, 0);
            }
        }
        #pragma unroll
        for (int rt = 0; rt < 3; ++rt)
            #pragma unroll
            for (int q = 0; q < 2; ++q) {
                int col = (wave * 2 + q) * 16 + (lane & 15);
                int row = rt * 16 + ((lane >> 4) << 2);
                #pragma unroll
                for (int r = 0; r < 4; ++r)
                    VU[(row + r) * LDSP + col] = f2s(acc[rt][q][r]);
            }
    }
    __syncthreads();

    // GEMM-V: VV = VU @ V -> XV
    {
        f32x4 acc[3][2];
        #pragma unroll
        for (int rt = 0; rt < 3; ++rt)
            #pragma unroll
            for (int q = 0; q < 2; ++q) acc[rt][q] = (f32x4){0.f, 0.f, 0.f, 0.f};
        for (int ks = 0; ks < 4; ++ks) {
            bf16x8 b[2];
            #pragma unroll
            for (int q = 0; q < 2; ++q)
                b[q] = ((const bf16x8*)Vp)[((size_t)ks * 8 + wave * 2 + q) * 64 + lane];
            #pragma unroll
            for (int rt = 0; rt < 3; ++rt) {
                bf16x8 a = *(const bf16x8*)&VU[(rt * 16 + (lane & 15)) * LDSP + ks * 32 + ((lane >> 4) << 3)];
                #pragma unroll
                for (int q = 0; q < 2; ++q)
                    acc[rt][q] = __builtin_amdgcn_mfma_f32_16x16x32_bf16(a, b[q], acc[rt][q], 0, 0, 0);
            }
        }
        __syncthreads();
        #pragma unroll
        for (int rt = 0; rt < 3; ++rt)
            #pragma unroll
            for (int q = 0; q < 2; ++q) {
                int col = (wave * 2 + q) * 16 + (lane & 15);
                int row = rt * 16 + ((lane >> 4) << 2);
                #pragma unroll
                for (int r = 0; r < 4; ++r)
                    XV[(row + r) * LDSP + col] = f2s(acc[rt][q][r]);
            }
    }
    __syncthreads();

    for (int i = t; i < 16 * 128; i += 256) {
        int nl = i >> 7, j = i & 127;
        float s = 0.f;
        #pragma unroll
        for (int c = 0; c < 3; ++c) {
            int q = 3 * j + c;
            float f = s2f(XV[(nl * 3 + (q >> 7)) * LDSP + (q & 127)]);
            s += f * f;
        }
        NRM[nl * LDSP + j] = f2s(sqrtf(s));
    }
    __syncthreads();

    // GEMM-Wu1: H1 = silu([NRM | S] @ Wu1 + bu1)
    {
        f32x4 acc[2];
        #pragma unroll
        for (int q = 0; q < 2; ++q) acc[q] = (f32x4){0.f, 0.f, 0.f, 0.f};
        for (int ks = 0; ks < 8; ++ks) {
            const short* asrc = (ks < 4) ? NRM : S;
            int k0 = (ks & 3) * 32;
            bf16x8 a = *(const bf16x8*)&asrc[(lane & 15) * LDSP + k0 + ((lane >> 4) << 3)];
            #pragma unroll
            for (int q = 0; q < 2; ++q) {
                bf16x8 b = ((const bf16x8*)Wu1p)[((size_t)ks * 8 + wave * 2 + q) * 64 + lane];
                acc[q] = __builtin_amdgcn_mfma_f32_16x16x32_bf16(a, b, acc[q], 0, 0, 0);
            }
        }
        #pragma unroll
        for (int q = 0; q < 2; ++q) {
            int col = (wave * 2 + q) * 16 + (lane & 15);
            int row = (lane >> 4) << 2;
            float bb = bu1[col];
            #pragma unroll
            for (int r = 0; r < 4; ++r)
                H1[(row + r) * LDSP + col] = f2s(silu_f(acc[q][r] + bb));
        }
    }
    __syncthreads();

    // GEMM-Wu2: A1 / A3 tiles
    {
        f32x4 acc[4];
        #pragma unroll
        for (int q = 0; q < 4; ++q) acc[q] = (f32x4){0.f, 0.f, 0.f, 0.f};
        for (int ks = 0; ks < 4; ++ks) {
            bf16x8 a = *(const bf16x8*)&H1[(lane & 15) * LDSP + ks * 32 + ((lane >> 4) << 3)];
            #pragma unroll
            for (int q = 0; q < 4; ++q) {
                int w = wave * 4 + q;
                int ctp = (w < 8) ? w : (16 + (w - 8));
                bf16x8 b = ((const bf16x8*)Wu2p)[((size_t)ks * 24 + ctp) * 64 + lane];
                acc[q] = __builtin_amdgcn_mfma_f32_16x16x32_bf16(a, b, acc[q], 0, 0, 0);
            }
        }
        #pragma unroll
        for (int q = 0; q < 4; ++q) {
            int w = wave * 4 + q;
            int colloc = (w & 7) * 16 + (lane & 15);
            int row = (lane >> 4) << 2;
            short* dst = (w < 8) ? A1 : A3;
            float bb = bu2[((w < 8) ? 0 : 256) + colloc];
            #pragma unroll
            for (int r = 0; r < 4; ++r)
                dst[(row + r) * LDSP + colloc] = f2s(acc[q][r] + bb);
        }
    }
    __syncthreads();

    for (int i = t; i < 16 * 128; i += 256) {
        int nl = i >> 7, j = i & 127;
        float a1v = s2f(A1[nl * LDSP + j]);
        float a3v = s2f(A3[nl * LDSP + j]);
        __hip_bfloat16* mrow = M2 + (size_t)(n0 + nl) * FEAT;
        float dot = 0.f;
        #pragma unroll
        for (int c = 0; c < 3; ++c) {
            int q = 3 * j + c;
            int rr = nl * 3 + (q >> 7), cc = q & 127;
            float vu_ = s2f(VU[rr * LDSP + cc]);
            float vv_ = s2f(XV[rr * LDSP + cc]);
            float vf = vu_ * a1v;
            dot += vf * vv_;
            mrow[c * 128 + j] = __float2bfloat16(vf);
        }
        mrow[384 + j] = __float2bfloat16(dot + a3v);
    }
}

// ================================================================ k_gather1
// Round-12 version verbatim (best measured: 73 us, VGPR 48, no spills).
__global__ __launch_bounds__(128, 4) void k_gather1(
    const float* __restrict__ x,
    const __hip_bfloat16* __restrict__ P1,
    const __hip_bfloat16* __restrict__ basis,
    const float* __restrict__ ea1,
    const float* __restrict__ W2, const float* __restrict__ b2,
    const int* __restrict__ cnt, const unsigned int* __restrict__ slot,
    float* __restrict__ out)
{
    __shared__ float ebl[CAP][NRBF];
    __shared__ float eall[CAP][3];
    __shared__ int srcl[CAP], ell[CAP];

    const int d = blockIdx.x, t = threadIdx.x;   // 128 threads

    float w2r0[NRBF], w2r1[NRBF], w2r2[NRBF];
    #pragma unroll
    for (int n = 0; n < NRBF; ++n) {
        w2r0[n] = W2[n * 384 + t];
        w2r1[n] = W2[n * 384 + 128 + t];
        w2r2[n] = W2[n * 384 + 256 + t];
    }
    const float b2a = b2[t], b2b = b2[128 + t], b2c = b2[256 + t];

    const int deg = min(cnt[d], CAP);
    if (t < deg) {
        unsigned int p = slot[d * CAP + t];
        srcl[t] = (int)(p & 16383u);
        ell[t]  = (int)(p >> 14);
    }
    __syncthreads();
    for (int i = t; i < deg * NRBF; i += 128)
        ebl[i / NRBF][i % NRBF] = __bfloat162float(basis[(size_t)ell[i / NRBF] * NRBF + (i % NRBF)]);
    for (int i = t; i < deg * 3; i += 128)
        eall[i / 3][i % 3] = ea1[(size_t)ell[i / 3] * 3 + (i % 3)];
    __syncthreads();

    float acc0 = 0.f, acc1 = 0.f, acc2 = 0.f, accs = 0.f;

    for (int base = 0; base < deg; base += 8) {
        // prefetch 8 edges x 12 B (one row stream, no pad)
        unsigned int f0[8], f1[8], f2[8];
        #pragma unroll
        for (int ee = 0; ee < 8; ++ee) {
            int idx = (base + ee < deg) ? (base + ee) : base;
            const unsigned int* rp =
                (const unsigned int*)((const char*)P1 + (size_t)srcl[idx] * 1536) + t * 3;
            f0[ee] = rp[0]; f1[ee] = rp[1]; f2[ee] = rp[2];
        }
        #pragma unroll
        for (int ee = 0; ee < 8; ++ee) {
            if (base + ee >= deg) break;     // uniform per block
            const int ix = base + ee;
            float ebA = b2a, ebB = b2b, ebC = b2c;
            #pragma unroll
            for (int n = 0; n < NRBF; ++n) {
                float e = ebl[ix][n];
                ebA += e * w2r0[n];
                ebB += e * w2r1[n];
                ebC += e * w2r2[n];
            }
            float a1 = asf(f0[ee] << 16), a2 = asf(f0[ee] & 0xffff0000u);
            float a3 = asf(f1[ee] << 16), x0 = asf(f1[ee] & 0xffff0000u);
            float x1 = asf(f2[ee] << 16), x2 = asf(f2[ee] & 0xffff0000u);
            float s1 = a1 * ebA;
            float s2 = a2 * ebB;
            float s3 = a3 * ebC;
            acc0 += x0 * s1 + s3 * eall[ix][0];
            acc1 += x1 * s1 + s3 * eall[ix][1];
            acc2 += x2 * s1 + s3 * eall[ix][2];
            accs += s2;
        }
    }

    const size_t ro = (size_t)d * FEAT;
    out[ro + 3 * t]     = x[ro + 3 * t]     + acc0;
    out[ro + 3 * t + 1] = x[ro + 3 * t + 1] + acc1;
    out[ro + 3 * t + 2] = x[ro + 3 * t + 2] + acc2;
    out[ro + 384 + t]   = x[ro + 384 + t]   + accs;
}

// ================================================================ k_gather2
// 4 groups x 64 lanes; each group covers a full 1KB M2 row per uint4 load;
// 4-deep prefetch (16 regs) — well under the spill cliff.
__global__ __launch_bounds__(256) void k_gather2(
    const __hip_bfloat16* __restrict__ M2,
    const int* __restrict__ cnt, const unsigned int* __restrict__ slot,
    float* __restrict__ out)
{
    __shared__ float part[4][FEAT];   // 8 KB
    __shared__ int sl[CAP];
    const int d = blockIdx.x, t = threadIdx.x;
    const int lane = t & 63, g = t >> 6;      // 4 groups of 64
    const int deg = min(cnt[d], CAP);
    if (t < deg) sl[t] = (int)(slot[d * CAP + t] & 16383u);
    __syncthreads();

    float a0 = 0.f, a1 = 0.f, a2 = 0.f, a3 = 0.f;
    float a4 = 0.f, a5 = 0.f, a6 = 0.f, a7 = 0.f;

    int i = g;
    for (; i + 12 < deg; i += 16) {
        uint4 v[4];
        #pragma unroll
        for (int q = 0; q < 4; ++q)
            v[q] = *(const uint4*)((const char*)M2 + (size_t)sl[i + 4 * q] * 1024 + lane * 16);
        #pragma unroll
        for (int q = 0; q < 4; ++q) {
            a0 += asf(v[q].x << 16); a1 += asf(v[q].x & 0xffff0000u);
            a2 += asf(v[q].y << 16); a3 += asf(v[q].y & 0xffff0000u);
            a4 += asf(v[q].z << 16); a5 += asf(v[q].z & 0xffff0000u);
            a6 += asf(v[q].w << 16); a7 += asf(v[q].w & 0xffff0000u);
        }
    }
    for (; i < deg; i += 4) {
        uint4 v = *(const uint4*)((const char*)M2 + (size_t)sl[i] * 1024 + lane * 16);
        a0 += asf(v.x << 16); a1 += asf(v.x & 0xffff0000u);
        a2 += asf(v.y << 16); a3 += asf(v.y & 0xffff0000u);
        a4 += asf(v.z << 16); a5 += asf(v.z & 0xffff0000u);
        a6 += asf(v.w << 16); a7 += asf(v.w & 0xffff0000u);
    }
    part[g][lane * 8]     = a0; part[g][lane * 8 + 1] = a1;
    part[g][lane * 8 + 2] = a2; part[g][lane * 8 + 3] = a3;
    part[g][lane * 8 + 4] = a4; part[g][lane * 8 + 5] = a5;
    part[g][lane * 8 + 6] = a6; part[g][lane * 8 + 7] = a7;
    __syncthreads();

    #pragma unroll
    for (int gi = 0; gi < 2; ++gi) {
        int gc = t + gi * 256;
        int m = (gc < 384) ? ((gc % 3) * 128 + gc / 3) : gc;
        out[(size_t)d * FEAT + gc] += part[0][m] + part[1][m] + part[2][m] + part[3][m];
    }
}

// =================================================================== launch
extern "C" void kernel_launch(void* const* d_in, const int* in_sizes, int n_in,
                              void* d_out, int out_size, void* d_ws, size_t ws_size,
                              hipStream_t stream) {
    (void)in_sizes; (void)n_in; (void)out_size; (void)ws_size;
    const float* x   = (const float*)d_in[0];
    const int*   ei  = (const int*)d_in[1];
    const float* ea1 = (const float*)d_in[2];
    const float* ea2 = (const float*)d_in[3];
    const float* W1  = (const float*)d_in[4];
    const float* b1  = (const float*)d_in[5];
    const float* W2  = (const float*)d_in[6];
    const float* b2  = (const float*)d_in[7];
    const float* W3  = (const float*)d_in[8];
    const float* b3  = (const float*)d_in[9];
    const float* U   = (const float*)d_in[10];
    const float* V   = (const float*)d_in[11];
    const float* Wu1 = (const float*)d_in[12];
    const float* bu1 = (const float*)d_in[13];
    const float* Wu2 = (const float*)d_in[14];
    const float* bu2 = (const float*)d_in[15];
    float* out = (float*)d_out;

    // ws layout (ws proven >= 165 MB in round 3; used ~35 MB)
    char* w = (char*)d_ws;
    __hip_bfloat16* P1    = (__hip_bfloat16*)w;                 // N*768*2 = 15,360,000
    __hip_bfloat16* M2    = (__hip_bfloat16*)(w + 15360000);    // N*512*2 = 10,240,000
    __hip_bfloat16* basis = (__hip_bfloat16*)(w + 25600000);    // E*20*2  =  6,400,000
    short* W1p  = (short*)(w + 32000000);
    short* W3p  = (short*)(w + 32032768);
    short* Upk  = (short*)(w + 32131072);
    short* Vpk  = (short*)(w + 32163840);
    short* Wu1p = (short*)(w + 32196608);
    short* Wu2p = (short*)(w + 32262144);
    int*          cnt  = (int*)(w + 32360448);                  // 40,000
    unsigned int* slot = (unsigned int*)(w + 32400448);         // N*CAP*4 = 2,560,000

    hipMemsetAsync(cnt, 0, N_NODES * sizeof(int), stream);
    k_prep    <<<88 + (N_EDGES + 255) / 256, 256, 0, stream>>>(
        W1, W3, U, V, Wu1, Wu2, W1p, W3p, Upk, Vpk, Wu1p, Wu2p,
        ei, ea2, cnt, slot, basis);

    k_A_mfma  <<<N_NODES / 16, 256, 0, stream>>>(x, W1p, b1, W3p, b3, P1);
    k_gather1 <<<N_NODES,      128, 0, stream>>>(x, P1, basis, ea1, W2, b2, cnt, slot, out);
    k_B_mfma  <<<N_NODES / 16, 256, 0, stream>>>(Upk, Vpk, Wu1p, bu1, Wu2p, bu2, out, M2);
    k_gather2 <<<N_NODES,      256, 0, stream>>>(M2, cnt, slot, out);
}